// Round 1
// 313.981 us; speedup vs baseline: 1.1053x; 1.1053x over previous
//
#include <hip/hip_runtime.h>

#define NTHREADS 512

// Geometry (fixed by the reference)
#define NB   4
#define HH   256
#define WW   256

// u16-unit LDS offsets. Total 40704 u16 = 81,408 B -> 2 blocks/CU (162,816 <= 163,840)
#define XF     0        // 8192 u16 bf16 x B-frags            (dead after stage 2)
#define HID    8192     // 7680 u16 f16 hid[64][10][12]       (dead after stage 2)
#define Q_U    15872    // 8192 u16 f16 [c][(slot^cs)*8+j]    (dead after stage 3)
#define K_U    24064    // 8192 u16 f16                       (dead after stage 3 -> BFRU)
#define V_U    32256    // 8192 u16 f16                       (dead after stage 5)
#define CORRU  0        // 8192 u16 f16 (alias XF)
#define REDU   8192     // 2048 u16 region for f32 partials (alias HID)
#define BFRU   24064    // 8192 u16 bf16 gated B-frags (alias K)
#define PBUFU  0        // 17408 u16 = 8704 f32 (alias XF/HID/Q-head — all dead in stage 6)
#define MU_U   40448    // 128 u16 = 64 f32
#define RS_U   40576    // 128 u16 = 64 f32
#define SMEM_U 40704

typedef short s16x8 __attribute__((ext_vector_type(8)));
typedef float f32x16 __attribute__((ext_vector_type(16)));
typedef _Float16 h16x8 __attribute__((ext_vector_type(8)));
typedef _Float16 h16x4 __attribute__((ext_vector_type(4)));
typedef _Float16 h16x2 __attribute__((ext_vector_type(2)));

__device__ inline unsigned short f2bf(float f) {      // RNE f32 -> bf16
    unsigned u = __builtin_bit_cast(unsigned, f);
    u += 0x7FFFu + ((u >> 16) & 1u);
    return (unsigned short)(u >> 16);
}
__device__ inline float bf2f(unsigned short s) {
    return __builtin_bit_cast(float, (unsigned)s << 16);
}
__device__ inline unsigned short f2h(float f) {
    _Float16 h = (_Float16)f;
    return __builtin_bit_cast(unsigned short, h);
}

// v_dot2_f32_f16: d = a.lo*b.lo + a.hi*b.hi + c  (f16 mul, f32 accumulate)
__device__ inline float fdot2(unsigned a, unsigned b, float c) {
#if __has_builtin(__builtin_amdgcn_fdot2)
    return __builtin_amdgcn_fdot2(__builtin_bit_cast(h16x2, a),
                                  __builtin_bit_cast(h16x2, b), c, false);
#else
    h16x2 av = __builtin_bit_cast(h16x2, a);
    h16x2 bv = __builtin_bit_cast(h16x2, b);
    return c + (float)av[0] * (float)bv[0] + (float)av[1] * (float)bv[1];
#endif
}

// ---- prepack: w1 + wout(hi/lo) -> bf16 MFMA A-fragment order in d_ws ----
__global__ __launch_bounds__(256)
void fsas_prepack(const float* __restrict__ w1, const float* __restrict__ wout,
                  unsigned short* __restrict__ ws)
{
    int t = blockIdx.x * 256 + threadIdx.x;   // 0..40959
    if (t < 24576) {
        int b = t & 7, ln = (t >> 3) & 63, ks = (t >> 9) & 3, mtc = t >> 11;
        int l32 = ln & 31, half = ln >> 5;
        int o = mtc * 32 + l32;
        int kk = ks * 16 + half * 8 + b;
        ws[t] = f2bf(w1[o * 64 + kk]);
    } else if (t < 40960) {
        int idx = t - 24576;
        int lo = idx >= 8192;
        if (lo) idx -= 8192;
        int b = idx & 7, ln = (idx >> 3) & 63, ks = (idx >> 9) & 7, mtp = idx >> 12;
        int l32 = ln & 31, half = ln >> 5;
        int o = mtp * 32 + l32;
        int kk = ks * 16 + half * 8 + b;
        float v = wout[o * 128 + kk];
        unsigned short hi = f2bf(v);
        ws[t] = lo ? f2bf(v - bf2f(hi)) : hi;
    }
}

__global__ __launch_bounds__(NTHREADS, 4)
void fsas_fused(const float* __restrict__ x,
                const float* __restrict__ wdw,   // [384][3][3]
                const unsigned short* __restrict__ wsu,
                const float* __restrict__ lnw,
                const float* __restrict__ lnb,
                float* __restrict__ out)
{
    __shared__ unsigned short su[SMEM_U];

    const int tid = threadIdx.x;
    const int wv  = tid >> 6;      // 0..7
    const int ln  = tid & 63;
    const int l32 = ln & 31, half = ln >> 5;
    // XCD-aware swizzle: 4096 blocks, 8 XCDs round-robin on dispatch index.
    // Each XCD gets 512 consecutive logical blocks = a contiguous 16x32-patch
    // strip, so halo cache lines are re-used out of the XCD-private L2.
    const int lin  = (blockIdx.z * 32 + blockIdx.y) * 32 + blockIdx.x;
    const int orig = (lin & 7) * 512 + (lin >> 3);
    const int pw = orig & 31;
    const int ph = (orig >> 5) & 31;
    const int b  = orig >> 10;
    const int h0  = ph * 8;
    const int w0  = pw * 8;

    // ---- 0) zero xfrag (pad pos 100..127 must be 0) ----
    {
        float* xfF = (float*)(su + XF);
        for (int i = tid; i < 4096; i += NTHREADS) xfF[i] = 0.f;
    }
    __syncthreads();

    // ---- 1) x tile (10x10 + halo) -> bf16 B-fragments ----
    for (int idx = tid; idx < 6400; idx += NTHREADS) {
        int c = idx / 100, pos = idx - c * 100;
        int r = pos / 10, q = pos - r * 10;
        int h = h0 - 1 + r, w = w0 - 1 + q;
        float v = 0.f;
        if ((unsigned)h < (unsigned)HH && (unsigned)w < (unsigned)WW)
            v = x[((b * 64 + c) * HH + h) * WW + w];
        int lane = (pos & 31) + 32 * ((c >> 3) & 1);
        int nt = pos >> 5, ks = c >> 4, bb = c & 7;
        su[XF + ((nt * 4 + ks) * 64 + lane) * 8 + bb] = f2bf(v);
    }
    __syncthreads();

    // ---- 2) six half-rounds: MFMA (64 out-ch) + depthwise 3x3 ----
    const s16x8* waf = (const s16x8*)wsu;
    const int mt2 = wv & 1, nt = (wv >> 1) & 3;
    const int pos = nt * 32 + l32;
    const int r10 = pos / 10, c10 = pos - r10 * 10;
    const int posoff = r10 * 12 + c10;
    const bool pvalid = pos < 100;
    for (int rnd = 0; rnd < 6; ++rnd) {
        {
            int mtc = rnd * 2 + mt2;
            f32x16 acc = {};
#pragma unroll
            for (int ks = 0; ks < 4; ++ks) {
                s16x8 afr = waf[(mtc * 4 + ks) * 64 + ln];
                s16x8 bfr = *(const s16x8*)(su + XF + ((nt * 4 + ks) * 64 + ln) * 8);
                acc = __builtin_amdgcn_mfma_f32_32x32x16_bf16(afr, bfr, acc, 0, 0, 0);
            }
            if (pvalid) {
#pragma unroll
                for (int rr = 0; rr < 16; ++rr) {
                    int o_l = mt2 * 32 + (rr & 3) + 8 * (rr >> 2) + 4 * half;
                    su[HID + o_l * 120 + posoff] = f2h(acc[rr]);
                }
            }
        }
        __syncthreads();

        {
            int oc = tid >> 3, py = tid & 7;          // oc 0..63 local
            const float* wr = wdw + (rnd * 64 + oc) * 9;
            float wgt[9];
#pragma unroll
            for (int t = 0; t < 9; ++t) wgt[t] = wr[t];
            const unsigned short* hb = su + HID + oc * 120 + py * 12;
            _Float16 hh[3][12];
#pragma unroll
            for (int rr = 0; rr < 3; ++rr) {
                uint2 ua = *(const uint2*)(hb + rr * 12);
                uint2 ub = *(const uint2*)(hb + rr * 12 + 4);
                uint2 uc = *(const uint2*)(hb + rr * 12 + 8);
                h16x4 a = __builtin_bit_cast(h16x4, ua);
                h16x4 bq = __builtin_bit_cast(h16x4, ub);
                h16x4 cq = __builtin_bit_cast(h16x4, uc);
#pragma unroll
                for (int t = 0; t < 4; ++t) { hh[rr][t] = a[t]; hh[rr][4 + t] = bq[t]; hh[rr][8 + t] = cq[t]; }
            }
            float o_[8];
#pragma unroll
            for (int px = 0; px < 8; ++px) {
                o_[px] = wgt[0] * (float)hh[0][px] + wgt[1] * (float)hh[0][px + 1] + wgt[2] * (float)hh[0][px + 2]
                       + wgt[3] * (float)hh[1][px] + wgt[4] * (float)hh[1][px + 1] + wgt[5] * (float)hh[1][px + 2]
                       + wgt[6] * (float)hh[2][px] + wgt[7] * (float)hh[2][px + 1] + wgt[8] * (float)hh[2][px + 2];
            }
            int buf = rnd >> 1;                        // 0=q 1=k 2=v
            int cb  = (rnd & 1) * 64 + oc;
            int cs  = cb & 7;
            unsigned short* dst = su + Q_U + buf * 8192 + cb * 64 + ((py ^ cs) * 8);
            uint4 o4;
            o4.x = (unsigned)f2h(o_[0]) | ((unsigned)f2h(o_[1]) << 16);
            o4.y = (unsigned)f2h(o_[2]) | ((unsigned)f2h(o_[3]) << 16);
            o4.z = (unsigned)f2h(o_[4]) | ((unsigned)f2h(o_[5]) << 16);
            o4.w = (unsigned)f2h(o_[6]) | ((unsigned)f2h(o_[7]) << 16);
            *(uint4*)dst = o4;
        }
        __syncthreads();
    }

    // ---- 3) 8x8 circular conv via v_dot2_f32_f16, 2 output rows per thread ----
    {
        int c = tid >> 2, i0 = tid & 3, cs = c & 7;
        const unsigned short* qr = su + Q_U + c * 64;
        const unsigned short* kr = su + K_U + c * 64;
        float o0[8] = {0.f,0.f,0.f,0.f,0.f,0.f,0.f,0.f};
        float o1[8] = {0.f,0.f,0.f,0.f,0.f,0.f,0.f,0.f};
#pragma unroll
        for (int a = 0; a < 8; ++a) {
            uint4 uq = *(const uint4*)(qr + ((a ^ cs) * 8));
            int k0 = (i0 - a) & 7, k1 = (i0 + 4 - a) & 7;
            uint4 uk0 = *(const uint4*)(kr + ((k0 ^ cs) * 8));
            uint4 uk1 = *(const uint4*)(kr + ((k1 ^ cs) * 8));
            unsigned qw[4]  = {uq.x,  uq.y,  uq.z,  uq.w};
            unsigned kw0[4] = {uk0.x, uk0.y, uk0.z, uk0.w};
            unsigned kw1[4] = {uk1.x, uk1.y, uk1.z, uk1.w};
            // krev[m] = (lo: k[m], hi: k[(m-1)&7]) so that
            // dot2(q[2p:2p+1], krev[(j-2p)&7]) = q[2p]*k[j-2p] + q[2p+1]*k[j-2p-1]
            unsigned kr0[8], kr1[8];
#pragma unroll
            for (int p = 0; p < 4; ++p) {
                kr0[2 * p]     = __builtin_amdgcn_perm(kw0[(p + 3) & 3], kw0[p], 0x07060100u);
                kr0[2 * p + 1] = __builtin_amdgcn_alignbit(kw0[p], kw0[p], 16);
                kr1[2 * p]     = __builtin_amdgcn_perm(kw1[(p + 3) & 3], kw1[p], 0x07060100u);
                kr1[2 * p + 1] = __builtin_amdgcn_alignbit(kw1[p], kw1[p], 16);
            }
#pragma unroll
            for (int j = 0; j < 8; ++j) {
#pragma unroll
                for (int p = 0; p < 4; ++p) {
                    o0[j] = fdot2(qw[p], kr0[(j - 2 * p) & 7], o0[j]);
                    o1[j] = fdot2(qw[p], kr1[(j - 2 * p) & 7], o1[j]);
                }
            }
        }
        uint4 a4, b4;
        a4.x = (unsigned)f2h(o0[0]) | ((unsigned)f2h(o0[1]) << 16);
        a4.y = (unsigned)f2h(o0[2]) | ((unsigned)f2h(o0[3]) << 16);
        a4.z = (unsigned)f2h(o0[4]) | ((unsigned)f2h(o0[5]) << 16);
        a4.w = (unsigned)f2h(o0[6]) | ((unsigned)f2h(o0[7]) << 16);
        b4.x = (unsigned)f2h(o1[0]) | ((unsigned)f2h(o1[1]) << 16);
        b4.y = (unsigned)f2h(o1[2]) | ((unsigned)f2h(o1[3]) << 16);
        b4.z = (unsigned)f2h(o1[4]) | ((unsigned)f2h(o1[5]) << 16);
        b4.w = (unsigned)f2h(o1[6]) | ((unsigned)f2h(o1[7]) << 16);
        *(uint4*)(su + CORRU + c * 64 + ((i0 ^ cs) * 8)) = a4;
        *(uint4*)(su + CORRU + c * 64 + (((i0 + 4) ^ cs) * 8)) = b4;
    }
    __syncthreads();

    // ---- 4) LayerNorm stats: 8 partial groups x 64 px ----
    {
        float* redF = (float*)(su + REDU);
        int px = tid & 63, grp = tid >> 6;     // grp 0..7
        int prow = px >> 3, pcol = px & 7;
        float s = 0.f, s2 = 0.f;
#pragma unroll
        for (int i = 0; i < 16; ++i) {
            int c = i * 8 + grp;
            float v = (float)__builtin_bit_cast(_Float16,
                        su[CORRU + c * 64 + ((prow ^ (c & 7)) * 8) + pcol]);
            s += v; s2 += v * v;
        }
        redF[grp * 64 + px] = s;
        redF[512 + grp * 64 + px] = s2;
    }
    __syncthreads();
    if (tid < 64) {
        float* redF = (float*)(su + REDU);
        float s = 0.f, s2 = 0.f;
#pragma unroll
        for (int g = 0; g < 8; ++g) {
            s  += redF[g * 64 + tid];
            s2 += redF[512 + g * 64 + tid];
        }
        float m = s * (1.f / 128.f);
        float var = s2 * (1.f / 128.f) - m * m;
        ((float*)(su + MU_U))[tid] = m;
        ((float*)(su + RS_U))[tid] = rsqrtf(var + 1e-5f);
    }
    __syncthreads();

    // ---- 5) normalize + affine + gate(v) -> bf16 B-fragments (2 ch per thread) ----
    {
        int py = tid & 7, c0 = (tid >> 3) * 2;
        const float* muF = (const float*)(su + MU_U);
        const float* rsF = (const float*)(su + RS_U);
        float4 m0 = *(const float4*)(muF + py * 8);
        float4 m1 = *(const float4*)(muF + py * 8 + 4);
        float4 r0 = *(const float4*)(rsF + py * 8);
        float4 r1 = *(const float4*)(rsF + py * 8 + 4);
        float mm[8] = {m0.x, m0.y, m0.z, m0.w, m1.x, m1.y, m1.z, m1.w};
        float rr[8] = {r0.x, r0.y, r0.z, r0.w, r1.x, r1.y, r1.z, r1.w};
#pragma unroll
        for (int cc = 0; cc < 2; ++cc) {
            int c = c0 + cc, cs = c & 7;
            uint4 cu = *(const uint4*)(su + CORRU + c * 64 + ((py ^ cs) * 8));
            uint4 vu = *(const uint4*)(su + V_U   + c * 64 + ((py ^ cs) * 8));
            h16x8 ch = __builtin_bit_cast(h16x8, cu);
            h16x8 vh = __builtin_bit_cast(h16x8, vu);
            float wc = lnw[c], bc = lnb[c];
            int base = BFRU + (((py >> 2) * 8 + (c >> 4)) * 64 + 8 * (py & 3) + 32 * ((c >> 3) & 1)) * 8 + (c & 7);
#pragma unroll
            for (int j = 0; j < 8; ++j) {
                float t = (((float)ch[j] - mm[j]) * rr[j] * wc + bc) * (float)vh[j];
                su[base + j * 8] = f2bf(t);
            }
        }
    }
    __syncthreads();

    // ---- 6) projection 128 -> 64 via MFMA (8 waves, 4-deep K, hi+lo wout) ----
    {
        int kseg = wv & 1, mtp = (wv >> 1) & 1, ntp = wv >> 2;  // ntp 0..1
        const s16x8* whi = (const s16x8*)(wsu + 24576);
        const s16x8* wlo = (const s16x8*)(wsu + 32768);
        f32x16 acc = {};
#pragma unroll
        for (int k2 = 0; k2 < 4; ++k2) {
            int ks = kseg * 4 + k2;
            s16x8 ah = whi[(mtp * 8 + ks) * 64 + ln];
            s16x8 al = wlo[(mtp * 8 + ks) * 64 + ln];
            s16x8 bfr = *(const s16x8*)(su + BFRU + ((ntp * 8 + ks) * 64 + ln) * 8);
            acc = __builtin_amdgcn_mfma_f32_32x32x16_bf16(ah, bfr, acc, 0, 0, 0);
            acc = __builtin_amdgcn_mfma_f32_32x32x16_bf16(al, bfr, acc, 0, 0, 0);
        }
        float* pbufF = (float*)(su + PBUFU);
        int seg = (ntp * 2 + mtp) * 2 + kseg;
#pragma unroll
        for (int r = 0; r < 16; ++r)
            pbufF[r * 544 + seg * 68 + ln] = acc[r];
    }
    __syncthreads();

    // ---- 7) combine 2 k-partials and store (2 units per thread) ----
    {
        const float* pbufF = (const float*)(su + PBUFU);
#pragma unroll
        for (int it = 0; it < 2; ++it) {
            int u = tid + it * NTHREADS;     // 0..1023
            int o = u >> 4, pg = u & 15;
            int mtp = o >> 5, row = o & 31;
            int rg = row >> 3, rem = row & 7, hf = rem >> 2, ii = rem & 3;
            int r = rg * 4 + ii;
            int px0 = pg * 4;
            int ntp = px0 >> 5;
            int lane0 = (px0 & 31) + 32 * hf;
            const float* pb = pbufF + r * 544 + ((ntp * 2 + mtp) * 2) * 68 + lane0;
            float4 s0 = *(const float4*)(pb);
            float4 s1 = *(const float4*)(pb + 68);
            float4 rr;
            rr.x = s0.x + s1.x; rr.y = s0.y + s1.y;
            rr.z = s0.z + s1.z; rr.w = s0.w + s1.w;
            int py = px0 >> 3, wx = px0 & 7;
            *(float4*)(out + (((size_t)(b * 64 + o) * HH) + h0 + py) * WW + w0 + wx) = rr;
        }
    }
}

extern "C" void kernel_launch(void* const* d_in, const int* in_sizes, int n_in,
                              void* d_out, int out_size, void* d_ws, size_t ws_size,
                              hipStream_t stream) {
    const float* x    = (const float*)d_in[0];
    const float* w1   = (const float*)d_in[1];
    const float* wdw  = (const float*)d_in[2];
    const float* wout = (const float*)d_in[3];
    const float* lnw  = (const float*)d_in[4];
    const float* lnb  = (const float*)d_in[5];
    float* o = (float*)d_out;
    unsigned short* ws = (unsigned short*)d_ws;

    fsas_prepack<<<160, 256, 0, stream>>>(w1, wout, ws);
    dim3 grid(32, 32, NB);
    fsas_fused<<<grid, dim3(NTHREADS), 0, stream>>>(x, wdw, ws, lnw, lnb, o);
}

// Round 2
// 298.563 us; speedup vs baseline: 1.1623x; 1.0516x over previous
//
#include <hip/hip_runtime.h>

#define NTHREADS 512

// Geometry (fixed by the reference)
#define NB   4
#define HH   256
#define WW   256

// u16-unit LDS offsets. Total 40704 u16 = 81,408 B -> 2 blocks/CU (162,816 <= 163,840)
// XF (x B-frags) is hoisted to registers right after stage 1, so its region
// doubles as the odd-round HID buffer, then CORR, then PBUF.
#define XF     0        // 8192 u16 bf16 x B-frags      (dead after reg-hoist)
#define HIDA   8192     // 7680 u16 f16 hid (even rnds)
#define HIDB   0        // 7680 u16 f16 hid (odd rnds, aliases XF)
#define Q_U    15872    // 8192 u16 f16 [c][(slot^cs)*8+j]    (dead after stage 3)
#define K_U    24064    // 8192 u16 f16                       (dead after stage 3 -> BFRU)
#define V_U    32256    // 8192 u16 f16                       (dead after stage 5)
#define CORRU  0        // 8192 u16 f16 (alias XF/HIDB, dead after stage 2)
#define REDU   8192     // 2048 u16 region for f32 partials (alias HIDA)
#define BFRU   24064    // 8192 u16 bf16 gated B-frags (alias K)
#define PBUFU  0        // 17408 u16 = 8704 f32 (alias CORR/REDU/Q-head — all dead in stage 6)
#define MU_U   40448    // 128 u16 = 64 f32
#define RS_U   40576    // 128 u16 = 64 f32
#define SMEM_U 40704

typedef short s16x8 __attribute__((ext_vector_type(8)));
typedef float f32x16 __attribute__((ext_vector_type(16)));
typedef _Float16 h16x8 __attribute__((ext_vector_type(8)));
typedef _Float16 h16x4 __attribute__((ext_vector_type(4)));
typedef _Float16 h16x2 __attribute__((ext_vector_type(2)));

__device__ inline unsigned short f2bf(float f) {      // RNE f32 -> bf16
    unsigned u = __builtin_bit_cast(unsigned, f);
    u += 0x7FFFu + ((u >> 16) & 1u);
    return (unsigned short)(u >> 16);
}
__device__ inline float bf2f(unsigned short s) {
    return __builtin_bit_cast(float, (unsigned)s << 16);
}
__device__ inline unsigned short f2h(float f) {
    _Float16 h = (_Float16)f;
    return __builtin_bit_cast(unsigned short, h);
}

// v_dot2_f32_f16: d = a.lo*b.lo + a.hi*b.hi + c  (f16 mul, f32 accumulate)
__device__ inline float fdot2(unsigned a, unsigned b, float c) {
#if __has_builtin(__builtin_amdgcn_fdot2)
    return __builtin_amdgcn_fdot2(__builtin_bit_cast(h16x2, a),
                                  __builtin_bit_cast(h16x2, b), c, false);
#else
    h16x2 av = __builtin_bit_cast(h16x2, a);
    h16x2 bv = __builtin_bit_cast(h16x2, b);
    return c + (float)av[0] * (float)bv[0] + (float)av[1] * (float)bv[1];
#endif
}

// ---- prepack: w1 + wout(hi/lo) -> bf16 MFMA A-fragment order in d_ws ----
__global__ __launch_bounds__(256)
void fsas_prepack(const float* __restrict__ w1, const float* __restrict__ wout,
                  unsigned short* __restrict__ ws)
{
    int t = blockIdx.x * 256 + threadIdx.x;   // 0..40959
    if (t < 24576) {
        int b = t & 7, ln = (t >> 3) & 63, ks = (t >> 9) & 3, mtc = t >> 11;
        int l32 = ln & 31, half = ln >> 5;
        int o = mtc * 32 + l32;
        int kk = ks * 16 + half * 8 + b;
        ws[t] = f2bf(w1[o * 64 + kk]);
    } else if (t < 40960) {
        int idx = t - 24576;
        int lo = idx >= 8192;
        if (lo) idx -= 8192;
        int b = idx & 7, ln = (idx >> 3) & 63, ks = (idx >> 9) & 7, mtp = idx >> 12;
        int l32 = ln & 31, half = ln >> 5;
        int o = mtp * 32 + l32;
        int kk = ks * 16 + half * 8 + b;
        float v = wout[o * 128 + kk];
        unsigned short hi = f2bf(v);
        ws[t] = lo ? f2bf(v - bf2f(hi)) : hi;
    }
}

__global__ __launch_bounds__(NTHREADS, 4)
void fsas_fused(const float* __restrict__ x,
                const float* __restrict__ wdw,   // [384][3][3]
                const unsigned short* __restrict__ wsu,
                const float* __restrict__ lnw,
                const float* __restrict__ lnb,
                float* __restrict__ out)
{
    __shared__ unsigned short su[SMEM_U];

    const int tid = threadIdx.x;
    const int wv  = tid >> 6;      // 0..7
    const int ln  = tid & 63;
    const int l32 = ln & 31, half = ln >> 5;
    // XCD-aware swizzle: 4096 blocks, 8 XCDs round-robin on dispatch index.
    // Each XCD gets 512 consecutive logical blocks = a contiguous 16x32-patch
    // strip, so halo cache lines are re-used out of the XCD-private L2.
    const int lin  = (blockIdx.z * 32 + blockIdx.y) * 32 + blockIdx.x;
    const int orig = (lin & 7) * 512 + (lin >> 3);
    const int pw = orig & 31;
    const int ph = (orig >> 5) & 31;
    const int b  = orig >> 10;
    const int h0  = ph * 8;
    const int w0  = pw * 8;

    // ---- 1) x tile (10x10 + halo) -> bf16 B-fragments; pad slots get 0 ----
    for (int idx = tid; idx < 8192; idx += NTHREADS) {
        int c = idx >> 7, pos = idx & 127;
        float v = 0.f;
        if (pos < 100) {
            int r = pos / 10, q = pos - r * 10;
            int h = h0 - 1 + r, w = w0 - 1 + q;
            if ((unsigned)h < (unsigned)HH && (unsigned)w < (unsigned)WW)
                v = x[((b * 64 + c) * HH + h) * WW + w];
        }
        int lane = (pos & 31) + 32 * ((c >> 3) & 1);
        int nt = pos >> 5, ks = c >> 4, bb = c & 7;
        su[XF + ((nt * 4 + ks) * 64 + lane) * 8 + bb] = f2bf(v);
    }
    __syncthreads();

    // ---- 2) six half-rounds: MFMA (64 out-ch) + depthwise 3x3 ----
    const s16x8* waf = (const s16x8*)wsu;
    const int mt2 = wv & 1, nt = (wv >> 1) & 3;
    const int pos = nt * 32 + l32;
    const int r10 = pos / 10, c10 = pos - r10 * 10;
    const int posoff = r10 * 12 + c10;
    const bool pvalid = pos < 100;

    // Hoist the (round-invariant) B-fragments into registers; XF LDS dies here.
    s16x8 breg[4];
#pragma unroll
    for (int ks = 0; ks < 4; ++ks)
        breg[ks] = *(const s16x8*)(su + XF + ((nt * 4 + ks) * 64 + ln) * 8);

#pragma unroll 2
    for (int rnd = 0; rnd < 6; ++rnd) {
        const int hid_base = (rnd & 1) ? HIDB : HIDA;   // double-buffered scratch
        {
            int mtc = rnd * 2 + mt2;
            f32x16 acc = {};
#pragma unroll
            for (int ks = 0; ks < 4; ++ks) {
                s16x8 afr = waf[(mtc * 4 + ks) * 64 + ln];
                acc = __builtin_amdgcn_mfma_f32_32x32x16_bf16(afr, breg[ks], acc, 0, 0, 0);
            }
            if (pvalid) {
#pragma unroll
                for (int rr = 0; rr < 16; ++rr) {
                    int o_l = mt2 * 32 + (rr & 3) + 8 * (rr >> 2) + 4 * half;
                    su[hid_base + o_l * 120 + posoff] = f2h(acc[rr]);
                }
            }
        }
        __syncthreads();
        // depthwise 3x3 on this round's 64 channels; no trailing barrier:
        // next round's MFMA writes the OTHER hid buffer, and the barrier at
        // the head of the next depthwise fences the round-r+2 overwrite.
        {
            int oc = tid >> 3, py = tid & 7;          // oc 0..63 local
            const float* wr = wdw + (rnd * 64 + oc) * 9;
            float wgt[9];
#pragma unroll
            for (int t = 0; t < 9; ++t) wgt[t] = wr[t];
            const unsigned short* hb = su + hid_base + oc * 120 + py * 12;
            _Float16 hh[3][12];
#pragma unroll
            for (int rr = 0; rr < 3; ++rr) {
                uint2 ua = *(const uint2*)(hb + rr * 12);
                uint2 ub = *(const uint2*)(hb + rr * 12 + 4);
                uint2 uc = *(const uint2*)(hb + rr * 12 + 8);
                h16x4 a = __builtin_bit_cast(h16x4, ua);
                h16x4 bq = __builtin_bit_cast(h16x4, ub);
                h16x4 cq = __builtin_bit_cast(h16x4, uc);
#pragma unroll
                for (int t = 0; t < 4; ++t) { hh[rr][t] = a[t]; hh[rr][4 + t] = bq[t]; hh[rr][8 + t] = cq[t]; }
            }
            float o_[8];
#pragma unroll
            for (int px = 0; px < 8; ++px) {
                o_[px] = wgt[0] * (float)hh[0][px] + wgt[1] * (float)hh[0][px + 1] + wgt[2] * (float)hh[0][px + 2]
                       + wgt[3] * (float)hh[1][px] + wgt[4] * (float)hh[1][px + 1] + wgt[5] * (float)hh[1][px + 2]
                       + wgt[6] * (float)hh[2][px] + wgt[7] * (float)hh[2][px + 1] + wgt[8] * (float)hh[2][px + 2];
            }
            int buf = rnd >> 1;                        // 0=q 1=k 2=v
            int cb  = (rnd & 1) * 64 + oc;
            int cs  = cb & 7;
            unsigned short* dst = su + Q_U + buf * 8192 + cb * 64 + ((py ^ cs) * 8);
            uint4 o4;
            o4.x = (unsigned)f2h(o_[0]) | ((unsigned)f2h(o_[1]) << 16);
            o4.y = (unsigned)f2h(o_[2]) | ((unsigned)f2h(o_[3]) << 16);
            o4.z = (unsigned)f2h(o_[4]) | ((unsigned)f2h(o_[5]) << 16);
            o4.w = (unsigned)f2h(o_[6]) | ((unsigned)f2h(o_[7]) << 16);
            *(uint4*)dst = o4;
        }
    }
    __syncthreads();   // fences round-5 hid reads before CORR overwrites region 0

    // ---- 3) 8x8 circular conv via v_dot2_f32_f16, 2 output rows per thread ----
    {
        int c = tid >> 2, i0 = tid & 3, cs = c & 7;
        const unsigned short* qr = su + Q_U + c * 64;
        const unsigned short* kr = su + K_U + c * 64;
        float o0[8] = {0.f,0.f,0.f,0.f,0.f,0.f,0.f,0.f};
        float o1[8] = {0.f,0.f,0.f,0.f,0.f,0.f,0.f,0.f};
#pragma unroll
        for (int a = 0; a < 8; ++a) {
            uint4 uq = *(const uint4*)(qr + ((a ^ cs) * 8));
            int k0 = (i0 - a) & 7, k1 = (i0 + 4 - a) & 7;
            uint4 uk0 = *(const uint4*)(kr + ((k0 ^ cs) * 8));
            uint4 uk1 = *(const uint4*)(kr + ((k1 ^ cs) * 8));
            unsigned qw[4]  = {uq.x,  uq.y,  uq.z,  uq.w};
            unsigned kw0[4] = {uk0.x, uk0.y, uk0.z, uk0.w};
            unsigned kw1[4] = {uk1.x, uk1.y, uk1.z, uk1.w};
            // krev[m] = (lo: k[m], hi: k[(m-1)&7]) so that
            // dot2(q[2p:2p+1], krev[(j-2p)&7]) = q[2p]*k[j-2p] + q[2p+1]*k[j-2p-1]
            unsigned kr0[8], kr1[8];
#pragma unroll
            for (int p = 0; p < 4; ++p) {
                kr0[2 * p]     = __builtin_amdgcn_perm(kw0[(p + 3) & 3], kw0[p], 0x07060100u);
                kr0[2 * p + 1] = __builtin_amdgcn_alignbit(kw0[p], kw0[p], 16);
                kr1[2 * p]     = __builtin_amdgcn_perm(kw1[(p + 3) & 3], kw1[p], 0x07060100u);
                kr1[2 * p + 1] = __builtin_amdgcn_alignbit(kw1[p], kw1[p], 16);
            }
#pragma unroll
            for (int j = 0; j < 8; ++j) {
#pragma unroll
                for (int p = 0; p < 4; ++p) {
                    o0[j] = fdot2(qw[p], kr0[(j - 2 * p) & 7], o0[j]);
                    o1[j] = fdot2(qw[p], kr1[(j - 2 * p) & 7], o1[j]);
                }
            }
        }
        uint4 a4, b4;
        a4.x = (unsigned)f2h(o0[0]) | ((unsigned)f2h(o0[1]) << 16);
        a4.y = (unsigned)f2h(o0[2]) | ((unsigned)f2h(o0[3]) << 16);
        a4.z = (unsigned)f2h(o0[4]) | ((unsigned)f2h(o0[5]) << 16);
        a4.w = (unsigned)f2h(o0[6]) | ((unsigned)f2h(o0[7]) << 16);
        b4.x = (unsigned)f2h(o1[0]) | ((unsigned)f2h(o1[1]) << 16);
        b4.y = (unsigned)f2h(o1[2]) | ((unsigned)f2h(o1[3]) << 16);
        b4.z = (unsigned)f2h(o1[4]) | ((unsigned)f2h(o1[5]) << 16);
        b4.w = (unsigned)f2h(o1[6]) | ((unsigned)f2h(o1[7]) << 16);
        *(uint4*)(su + CORRU + c * 64 + ((i0 ^ cs) * 8)) = a4;
        *(uint4*)(su + CORRU + c * 64 + (((i0 + 4) ^ cs) * 8)) = b4;
    }
    __syncthreads();

    // ---- 4) LayerNorm stats: 8 partial groups x 64 px ----
    {
        float* redF = (float*)(su + REDU);
        int px = tid & 63, grp = tid >> 6;     // grp 0..7
        int prow = px >> 3, pcol = px & 7;
        float s = 0.f, s2 = 0.f;
#pragma unroll
        for (int i = 0; i < 16; ++i) {
            int c = i * 8 + grp;
            float v = (float)__builtin_bit_cast(_Float16,
                        su[CORRU + c * 64 + ((prow ^ (c & 7)) * 8) + pcol]);
            s += v; s2 += v * v;
        }
        redF[grp * 64 + px] = s;
        redF[512 + grp * 64 + px] = s2;
    }
    __syncthreads();
    if (tid < 64) {
        float* redF = (float*)(su + REDU);
        float s = 0.f, s2 = 0.f;
#pragma unroll
        for (int g = 0; g < 8; ++g) {
            s  += redF[g * 64 + tid];
            s2 += redF[512 + g * 64 + tid];
        }
        float m = s * (1.f / 128.f);
        float var = s2 * (1.f / 128.f) - m * m;
        ((float*)(su + MU_U))[tid] = m;
        ((float*)(su + RS_U))[tid] = rsqrtf(var + 1e-5f);
    }
    __syncthreads();

    // ---- 5) normalize + affine + gate(v) -> bf16 B-fragments (2 ch per thread) ----
    {
        int py = tid & 7, c0 = (tid >> 3) * 2;
        const float* muF = (const float*)(su + MU_U);
        const float* rsF = (const float*)(su + RS_U);
        float4 m0 = *(const float4*)(muF + py * 8);
        float4 m1 = *(const float4*)(muF + py * 8 + 4);
        float4 r0 = *(const float4*)(rsF + py * 8);
        float4 r1 = *(const float4*)(rsF + py * 8 + 4);
        float mm[8] = {m0.x, m0.y, m0.z, m0.w, m1.x, m1.y, m1.z, m1.w};
        float rr[8] = {r0.x, r0.y, r0.z, r0.w, r1.x, r1.y, r1.z, r1.w};
#pragma unroll
        for (int cc = 0; cc < 2; ++cc) {
            int c = c0 + cc, cs = c & 7;
            uint4 cu = *(const uint4*)(su + CORRU + c * 64 + ((py ^ cs) * 8));
            uint4 vu = *(const uint4*)(su + V_U   + c * 64 + ((py ^ cs) * 8));
            h16x8 ch = __builtin_bit_cast(h16x8, cu);
            h16x8 vh = __builtin_bit_cast(h16x8, vu);
            float wc = lnw[c], bc = lnb[c];
            int base = BFRU + (((py >> 2) * 8 + (c >> 4)) * 64 + 8 * (py & 3) + 32 * ((c >> 3) & 1)) * 8 + (c & 7);
#pragma unroll
            for (int j = 0; j < 8; ++j) {
                float t = (((float)ch[j] - mm[j]) * rr[j] * wc + bc) * (float)vh[j];
                su[base + j * 8] = f2bf(t);
            }
        }
    }
    __syncthreads();

    // ---- 6) projection 128 -> 64 via MFMA (8 waves, 4-deep K, hi+lo wout) ----
    {
        int kseg = wv & 1, mtp = (wv >> 1) & 1, ntp = wv >> 2;  // ntp 0..1
        const s16x8* whi = (const s16x8*)(wsu + 24576);
        const s16x8* wlo = (const s16x8*)(wsu + 32768);
        f32x16 acc = {};
#pragma unroll
        for (int k2 = 0; k2 < 4; ++k2) {
            int ks = kseg * 4 + k2;
            s16x8 ah = whi[(mtp * 8 + ks) * 64 + ln];
            s16x8 al = wlo[(mtp * 8 + ks) * 64 + ln];
            s16x8 bfr = *(const s16x8*)(su + BFRU + ((ntp * 8 + ks) * 64 + ln) * 8);
            acc = __builtin_amdgcn_mfma_f32_32x32x16_bf16(ah, bfr, acc, 0, 0, 0);
            acc = __builtin_amdgcn_mfma_f32_32x32x16_bf16(al, bfr, acc, 0, 0, 0);
        }
        float* pbufF = (float*)(su + PBUFU);
        int seg = (ntp * 2 + mtp) * 2 + kseg;
#pragma unroll
        for (int r = 0; r < 16; ++r)
            pbufF[r * 544 + seg * 68 + ln] = acc[r];
    }
    __syncthreads();

    // ---- 7) combine 2 k-partials and store (2 units per thread) ----
    {
        const float* pbufF = (const float*)(su + PBUFU);
#pragma unroll
        for (int it = 0; it < 2; ++it) {
            int u = tid + it * NTHREADS;     // 0..1023
            int o = u >> 4, pg = u & 15;
            int mtp = o >> 5, row = o & 31;
            int rg = row >> 3, rem = row & 7, hf = rem >> 2, ii = rem & 3;
            int r = rg * 4 + ii;
            int px0 = pg * 4;
            int ntp = px0 >> 5;
            int lane0 = (px0 & 31) + 32 * hf;
            const float* pb = pbufF + r * 544 + ((ntp * 2 + mtp) * 2) * 68 + lane0;
            float4 s0 = *(const float4*)(pb);
            float4 s1 = *(const float4*)(pb + 68);
            float4 rr;
            rr.x = s0.x + s1.x; rr.y = s0.y + s1.y;
            rr.z = s0.z + s1.z; rr.w = s0.w + s1.w;
            int py = px0 >> 3, wx = px0 & 7;
            *(float4*)(out + (((size_t)(b * 64 + o) * HH) + h0 + py) * WW + w0 + wx) = rr;
        }
    }
}

extern "C" void kernel_launch(void* const* d_in, const int* in_sizes, int n_in,
                              void* d_out, int out_size, void* d_ws, size_t ws_size,
                              hipStream_t stream) {
    const float* x    = (const float*)d_in[0];
    const float* w1   = (const float*)d_in[1];
    const float* wdw  = (const float*)d_in[2];
    const float* wout = (const float*)d_in[3];
    const float* lnw  = (const float*)d_in[4];
    const float* lnb  = (const float*)d_in[5];
    float* o = (float*)d_out;
    unsigned short* ws = (unsigned short*)d_ws;

    fsas_prepack<<<160, 256, 0, stream>>>(w1, wout, ws);
    dim3 grid(32, 32, NB);
    fsas_fused<<<grid, dim3(NTHREADS), 0, stream>>>(x, wdw, ws, lnw, lnb, o);
}